// Round 9
// baseline (271.577 us; speedup 1.0000x reference)
//
#include <hip/hip_runtime.h>

#define L_NODES 100000
#define NFEAT   256
#define JDIM    128

typedef __bf16 bf16x8 __attribute__((ext_vector_type(8)));
typedef __bf16 bf16x4 __attribute__((ext_vector_type(4)));
typedef float  floatx4 __attribute__((ext_vector_type(4)));

// ---------------------------------------------------------------------------
// R20: k_prep ELIMINATED.  Both kernels build their MFMA B-panels directly
// from the fp32 weights (strided 8-load gather + cvt per fragment, batched
// 8/4 fragments per latency exposure).  Panels are L2-resident (128 KB) so
// the extra requests are ~free; saves one kernel launch + workspace round.
//
// Fragment math (unchanged semantics):
//   b1 [nt][ks][j] = Wh[(ks*32+lq*8+j)*128 + n],  n  = (wave*2+nt)*16+lm
//   b2h[nt][ks][j] = n2<128 ? Wg[(k0+j)*128+n2] : Wg[(128+k0+j)*128+n2-128]
//                    k0 = ks*32+lq*8,             n2 = (wave*4+h*2+nt)*16+lm
//   b3 [nt][ks][j] = Wg[(128+ks*32+lq*8+j)*128 + n], n = (wave*2+nt)*16+lm
// ---------------------------------------------------------------------------

// ---------------------------------------------------------------------------
// Kernel 1 (fused h1+uv).  BM=128 (R19 structure kept: one Sm[128x264],
// As/Hs/Os aliased, 5 barriers, 32 batched NT X-loads, phase-2 two halves).
// ---------------------------------------------------------------------------
__global__ __launch_bounds__(256, 2) void k_h1uv(
    const float* __restrict__ X, const float* __restrict__ Wh,
    const float* __restrict__ Wg, const float* __restrict__ b,
    __bf16* __restrict__ U, __bf16* __restrict__ V)
{
    __shared__ __bf16 Sm[128 * 264];  // As (stride 264) / Hs (stride 136) / Os

    const int tid  = threadIdx.x;
    const int row0 = blockIdx.x * 128;
    const int wave = tid >> 6, lane = tid & 63;
    const int lm = lane & 15, lq = lane >> 4;

    // ---- stage X tile: all 32 loads in flight (NT), then cvt+write ----
    floatx4 xa[32];
    #pragma unroll
    for (int it = 0; it < 32; ++it) {
        int f4  = it * 256 + tid;                 // 0..8191
        int row = f4 >> 6, c4 = f4 & 63;
        int grow = row0 + row; if (grow >= L_NODES) grow = L_NODES - 1;
        xa[it] = __builtin_nontemporal_load(
                     reinterpret_cast<const floatx4*>(X + (size_t)grow * NFEAT + c4 * 4));
    }
    #pragma unroll
    for (int it = 0; it < 32; ++it) {
        int f4  = it * 256 + tid;
        int row = f4 >> 6, c4 = f4 & 63;
        bf16x4 o;
        o[0]=(__bf16)xa[it][0]; o[1]=(__bf16)xa[it][1];
        o[2]=(__bf16)xa[it][2]; o[3]=(__bf16)xa[it][3];
        *(bf16x4*)&Sm[row * 264 + c4 * 4] = o;
    }

    // b1 panel built from Wh directly: 2 batches of 8 frags (64 loads each).
    bf16x8 b1[2][8];
    #pragma unroll
    for (int nt = 0; nt < 2; ++nt) {
        const int n = (wave * 2 + nt) * 16 + lm;
        float w[8][8];
        #pragma unroll
        for (int ks = 0; ks < 8; ++ks)
            #pragma unroll
            for (int j = 0; j < 8; ++j)
                w[ks][j] = Wh[(size_t)(ks * 32 + lq * 8 + j) * JDIM + n];
        #pragma unroll
        for (int ks = 0; ks < 8; ++ks) {
            bf16x8 o;
            #pragma unroll
            for (int j = 0; j < 8; ++j) o[j] = (__bf16)w[ks][j];
            b1[nt][ks] = o;
        }
    }
    __syncthreads();                                          // bar1: As ready

    // ---- phase 1: H = relu(X @ Wh + b), 128 rows ----
    floatx4 acc1[8][2] = {};
    #pragma unroll
    for (int ks = 0; ks < 8; ++ks) {
        bf16x8 af[8];
        #pragma unroll
        for (int t = 0; t < 8; ++t)
            af[t] = *(const bf16x8*)&Sm[(t * 16 + lm) * 264 + ks * 32 + lq * 8];
        #pragma unroll
        for (int t = 0; t < 8; ++t)
            #pragma unroll
            for (int nt = 0; nt < 2; ++nt)
                acc1[t][nt] = __builtin_amdgcn_mfma_f32_16x16x32_bf16(
                    af[t], b1[nt][ks], acc1[t][nt], 0, 0, 0);
    }
    __syncthreads();                                          // bar2: As reads closed

    // write Hs (stride 136; aliases As — As dead)
    #pragma unroll
    for (int nt = 0; nt < 2; ++nt) {
        int col = (wave * 2 + nt) * 16 + lm;
        float bias = b[col];
        #pragma unroll
        for (int t = 0; t < 8; ++t)
            #pragma unroll
            for (int p = 0; p < 4; ++p)
                Sm[(t * 16 + lq * 4 + p) * 136 + col] =
                    (__bf16)fmaxf(acc1[t][nt][p] + bias, 0.f);
    }
    __syncthreads();                                          // bar3: Hs ready

    // ---- phase 2: two ks-passes (h=0,1); both acc halves stay live ----
    floatx4 acc2a[8][2] = {}, acc2b[8][2] = {};
    #pragma unroll
    for (int h = 0; h < 2; ++h) {
        bf16x8 b2h[2][4];
        #pragma unroll
        for (int nt = 0; nt < 2; ++nt) {
            const int n2 = (wave * 4 + h * 2 + nt) * 16 + lm;
            const float* wsrc = (n2 < 128) ? (Wg + n2)
                                           : (Wg + (size_t)128 * JDIM + (n2 - 128));
            float w[4][8];
            #pragma unroll
            for (int ks = 0; ks < 4; ++ks)
                #pragma unroll
                for (int j = 0; j < 8; ++j)
                    w[ks][j] = wsrc[(size_t)(ks * 32 + lq * 8 + j) * JDIM];
            #pragma unroll
            for (int ks = 0; ks < 4; ++ks) {
                bf16x8 o;
                #pragma unroll
                for (int j = 0; j < 8; ++j) o[j] = (__bf16)w[ks][j];
                b2h[nt][ks] = o;
            }
        }
        #pragma unroll
        for (int ks = 0; ks < 4; ++ks) {
            bf16x8 af[8];
            #pragma unroll
            for (int t = 0; t < 8; ++t)
                af[t] = *(const bf16x8*)&Sm[(t * 16 + lm) * 136 + ks * 32 + lq * 8];
            #pragma unroll
            for (int t = 0; t < 8; ++t)
                #pragma unroll
                for (int nt = 0; nt < 2; ++nt) {
                    floatx4* acc = h ? &acc2b[t][nt] : &acc2a[t][nt];
                    *acc = __builtin_amdgcn_mfma_f32_16x16x32_bf16(
                        af[t], b2h[nt][ks], *acc, 0, 0, 0);
                }
        }
    }
    __syncthreads();                                          // bar4: Hs reads closed

    // write Os (stride 264; aliases Hs — Hs dead)
    #pragma unroll
    for (int h = 0; h < 2; ++h)
        #pragma unroll
        for (int nt = 0; nt < 2; ++nt) {
            int col = (wave * 4 + h * 2 + nt) * 16 + lm;
            #pragma unroll
            for (int t = 0; t < 8; ++t)
                #pragma unroll
                for (int p = 0; p < 4; ++p)
                    Sm[(t * 16 + lq * 4 + p) * 264 + col] =
                        (__bf16)(h ? acc2b[t][nt][p] : acc2a[t][nt][p]);
        }
    __syncthreads();                                          // bar5: Os ready

    // coalesced store of U|V from Os
    #pragma unroll
    for (int it = 0; it < 16; ++it) {
        int fid = it * 256 + tid;                 // 0..4095
        int row = fid >> 5, c8 = fid & 31;
        int grow = row0 + row;
        if (grow < L_NODES) {
            int col = c8 * 8;
            bf16x8 v = *(bf16x8*)&Sm[row * 264 + col];
            if (col < 128) *(bf16x8*)(U + (size_t)grow * JDIM + col) = v;
            else           *(bf16x8*)(V + (size_t)grow * JDIM + (col - 128)) = v;
        }
    }
}

// ---------------------------------------------------------------------------
// Kernel 2 (fused gather + final).  67.3 us = request-volume ceiling (410 MB
// at ~6.1 TB/s service).  R20 change: b3 built from Wg directly (2 batches
// of 4 frags), removing the WtGv dependency.  Structure otherwise unchanged.
// ---------------------------------------------------------------------------
__global__ __launch_bounds__(256, 4) void k_gfinal(
    const __bf16* __restrict__ U, const __bf16* __restrict__ V,
    const float* __restrict__ Wg, const float* __restrict__ bg,
    const float* __restrict__ Wf, const float* __restrict__ bf,
    const int* __restrict__ idx0, const int* __restrict__ idx1,
    float* __restrict__ out)
{
    __shared__ int    sidx[2][8][64];               // 4 KB; part[] aliases this
    __shared__ __bf16 E1s[64 * 136];                // 17.4 KB
    __shared__ __bf16 Us [64 * 136];                // 17.4 KB
    float (*part)[64][2] = (float (*)[64][2])&sidx[0][0][0];   // 2 KB alias

    const int tid  = threadIdx.x;
    const int row0 = blockIdx.x * 64;
    const int wave = tid >> 6, lane = tid & 63;
    const int lm = lane & 15, lq = lane >> 4;

    // stage indices (1024 ints, 4/thread, NT) and U tile (4 bf16x8/thread)
    #pragma unroll
    for (int it = 0; it < 4; ++it) {
        int fid = it * 256 + tid;                 // 0..1023
        int m = fid >> 9, rem = fid & 511;
        int s = rem >> 6, il = rem & 63;
        int gr = row0 + il; if (gr >= L_NODES) gr = L_NODES - 1;
        const int* ip = (m ? idx1 : idx0) + (size_t)s * L_NODES + gr;
        sidx[m][s][il] = __builtin_nontemporal_load(ip);
    }
    #pragma unroll
    for (int it = 0; it < 4; ++it) {
        int fid = it * 256 + tid;                 // 0..1023
        int r = fid >> 4, c8 = fid & 15;
        int g = row0 + r; if (g >= L_NODES) g = L_NODES - 1;
        *(bf16x8*)&Us[r * 136 + c8 * 8] = *(const bf16x8*)(U + (size_t)g * JDIM + c8 * 8);
    }
    __syncthreads();

    // ---- phase A: gather-add into E1s (2-deep pipelined) ----
    {
        const int c0 = (tid & 15) * 8;            // col chunk
        const int rb = tid >> 4;                  // row base 0..15 (+16k)
        float bias[8];
        *(float4*)&bias[0] = *(const float4*)(bg + c0);
        *(float4*)&bias[4] = *(const float4*)(bg + c0 + 4);

        float acc[4][8] = {};
        bf16x8 uA[4], vA[4], uB[4], vB[4];

        auto LOADP = [&](int s, bf16x8 (&uu)[4], bf16x8 (&vv)[4]) {
            #pragma unroll
            for (int rr = 0; rr < 4; ++rr) {
                int r = rb + rr * 16;
                int a0 = sidx[0][s][r], a1 = sidx[1][s][r];
                uu[rr] = *(const bf16x8*)(U + (size_t)a0 * JDIM + c0);
                vv[rr] = *(const bf16x8*)(V + (size_t)a1 * JDIM + c0);
            }
        };
        auto ACCUM = [&](bf16x8 (&uu)[4], bf16x8 (&vv)[4]) {
            #pragma unroll
            for (int rr = 0; rr < 4; ++rr)
                #pragma unroll
                for (int p = 0; p < 8; ++p)
                    acc[rr][p] += fmaxf((float)uu[rr][p] + (float)vv[rr][p] + bias[p], 0.f);
        };

        LOADP(0, uA, vA);
        #pragma unroll
        for (int s = 0; s < 8; ++s) {
            if ((s & 1) == 0) {
                if (s < 7) LOADP(s + 1, uB, vB);
                ACCUM(uA, vA);
            } else {
                if (s < 7) LOADP(s + 1, uA, vA);
                ACCUM(uB, vB);
            }
        }

        #pragma unroll
        for (int rr = 0; rr < 4; ++rr) {
            int r = rb + rr * 16;
            bf16x8 o;
            #pragma unroll
            for (int p = 0; p < 8; ++p)
                o[p] = (__bf16)fmaxf(acc[rr][p] * 0.125f, 0.f);
            *(bf16x8*)&E1s[r * 136 + c0] = o;
        }
    }
    __syncthreads();   // also closes all sidx reads before part[] writes

    // B panel (phase-B-only) built from Wg: 2 batches of 4 frags.
    bf16x8 b3[2][4];
    #pragma unroll
    for (int nt = 0; nt < 2; ++nt) {
        const int n = (wave * 2 + nt) * 16 + lm;
        float w[4][8];
        #pragma unroll
        for (int ks = 0; ks < 4; ++ks)
            #pragma unroll
            for (int j = 0; j < 8; ++j)
                w[ks][j] = Wg[(size_t)(128 + ks * 32 + lq * 8 + j) * JDIM + n];
        #pragma unroll
        for (int ks = 0; ks < 4; ++ks) {
            bf16x8 o;
            #pragma unroll
            for (int j = 0; j < 8; ++j) o[j] = (__bf16)w[ks][j];
            b3[nt][ks] = o;
        }
    }

    // ---- phase B: E2 = relu(U + E1 @ Wg_bot + bg); head ----
    floatx4 acc[4][2] = {};
    #pragma unroll
    for (int ks = 0; ks < 4; ++ks) {
        bf16x8 af[4];
        #pragma unroll
        for (int t = 0; t < 4; ++t)
            af[t] = *(const bf16x8*)&E1s[(t * 16 + lm) * 136 + ks * 32 + lq * 8];
        #pragma unroll
        for (int t = 0; t < 4; ++t)
            #pragma unroll
            for (int nt = 0; nt < 2; ++nt)
                acc[t][nt] = __builtin_amdgcn_mfma_f32_16x16x32_bf16(
                    af[t], b3[nt][ks], acc[t][nt], 0, 0, 0);
    }

    float bias[2], wf0[2], wf1[2];
    #pragma unroll
    for (int nt = 0; nt < 2; ++nt) {
        int col = (wave * 2 + nt) * 16 + lm;
        bias[nt] = bg[col];
        wf0[nt] = Wf[col * 2 + 0];
        wf1[nt] = Wf[col * 2 + 1];
    }
    #pragma unroll
    for (int t = 0; t < 4; ++t) {
        float p0[4], p1[4];
        #pragma unroll
        for (int p = 0; p < 4; ++p) {
            int r = t * 16 + lq * 4 + p;
            float a0 = 0.f, a1 = 0.f;
            #pragma unroll
            for (int nt = 0; nt < 2; ++nt) {
                int col = (wave * 2 + nt) * 16 + lm;
                float e2 = fmaxf((float)Us[r * 136 + col] + acc[t][nt][p] + bias[nt], 0.f);
                a0 = fmaf(e2, wf0[nt], a0);
                a1 = fmaf(e2, wf1[nt], a1);
            }
            p0[p] = a0; p1[p] = a1;
        }
        #pragma unroll
        for (int m = 1; m <= 8; m <<= 1)
            #pragma unroll
            for (int p = 0; p < 4; ++p) {
                p0[p] += __shfl_xor(p0[p], m, 16);
                p1[p] += __shfl_xor(p1[p], m, 16);
            }
        if (lm == 0)
            #pragma unroll
            for (int p = 0; p < 4; ++p) {
                part[wave][t * 16 + lq * 4 + p][0] = p0[p];
                part[wave][t * 16 + lq * 4 + p][1] = p1[p];
            }
    }
    __syncthreads();

    if (tid < 128) {
        int row = tid >> 1, o = tid & 1;
        int grow = row0 + row;
        if (grow < L_NODES) {
            float v = part[0][row][o] + part[1][row][o] + part[2][row][o]
                    + part[3][row][o] + bf[o];
            __builtin_nontemporal_store(v, &out[(size_t)grow * 2 + o]);
        }
    }
}

// ---------------------------------------------------------------------------
extern "C" void kernel_launch(void* const* d_in, const int* in_sizes, int n_in,
                              void* d_out, int out_size, void* d_ws, size_t ws_size,
                              hipStream_t stream) {
    const float* X    = (const float*)d_in[0];
    const float* W_h1 = (const float*)d_in[1];
    const float* b_h1 = (const float*)d_in[2];
    const float* W_g1 = (const float*)d_in[3];
    const float* b_g1 = (const float*)d_in[4];
    const float* W_f  = (const float*)d_in[5];
    const float* b_f  = (const float*)d_in[6];
    const int*   idx0 = (const int*)d_in[7];
    const int*   idx1 = (const int*)d_in[8];
    float* out = (float*)d_out;

    __bf16* U = (__bf16*)d_ws;                    // 25.6 MB
    __bf16* V = U + (size_t)L_NODES * JDIM;       // 25.6 MB

    k_h1uv<<<(L_NODES + 127) / 128, 256, 0, stream>>>(X, W_h1, W_g1, b_h1, U, V);
    k_gfinal<<<(L_NODES + 63) / 64, 256, 0, stream>>>(U, V, W_g1, b_g1, W_f, b_f,
                                                      idx0, idx1, out);
}

// Round 10
// 225.688 us; speedup vs baseline: 1.2033x; 1.2033x over previous
//
#include <hip/hip_runtime.h>

#define L_NODES 100000
#define NFEAT   256
#define JDIM    128

typedef __bf16 bf16x8 __attribute__((ext_vector_type(8)));
typedef __bf16 bf16x4 __attribute__((ext_vector_type(4)));
typedef float  floatx4 __attribute__((ext_vector_type(4)));
typedef float  floatx2 __attribute__((ext_vector_type(2)));

// fp8 (OCP e4m3) pack/unpack via ISA ops (gfx940+; builtins less trustworthy).
__device__ inline floatx2 fp8x2_to_f32x2(unsigned int w) {   // decodes bits[15:0]
    floatx2 r;
    asm("v_cvt_pk_f32_fp8 %0, %1" : "=v"(r) : "v"(w));
    return r;
}
__device__ inline unsigned int f32x2_to_fp8x2(float a, float b) {  // pair in bits[15:0]
    unsigned int r;
    asm("v_cvt_pk_fp8_f32 %0, %1, %2" : "=v"(r) : "v"(a), "v"(b));
    return r;
}

// ---------------------------------------------------------------------------
// Prep (RESTORED — R20's in-kernel panel build cost +8us: 16x-uncoalesced):
//   WtH [128][256]: WtH[n][k]  = bf16(W_h1[k][n])
//   WtG2[256][128]: n<128: Wg[k][n] (U cols); n>=128: Wg[128+k][n-128] (V cols)
//     rows 128.. of WtG2 double as WtGv[n][k]=Wg[128+k][n] for k_gfinal.
// ---------------------------------------------------------------------------
__global__ __launch_bounds__(256) void k_prep(
    const float* __restrict__ Wh, const float* __restrict__ Wg,
    __bf16* __restrict__ WtH, __bf16* __restrict__ WtG2)
{
    int i = blockIdx.x * 256 + threadIdx.x;   // 32768
    int n = i >> 8, k = i & 255;
    WtH[i] = (__bf16)Wh[k * JDIM + n];
    int n2 = i >> 7, k2 = i & 127;
    WtG2[i] = (n2 < 128) ? (__bf16)Wg[k2 * JDIM + n2]
                         : (__bf16)Wg[(128 + k2) * JDIM + (n2 - 128)];
}

// ---------------------------------------------------------------------------
// Kernel 1 (fused h1+uv), R19 structure (BM=128, Sm aliased, 5 barriers,
// batched NT X staging).  R21 change: output stores are U-bf16 + U-fp8 +
// V-fp8 (V-bf16 dropped — it was only ever gather-read).  Total write
// volume unchanged (25.6 + 12.8 + 12.8 MB).
// ---------------------------------------------------------------------------
__global__ __launch_bounds__(256, 2) void k_h1uv(
    const float* __restrict__ X, const __bf16* __restrict__ WtH,
    const __bf16* __restrict__ WtG2, const float* __restrict__ b,
    __bf16* __restrict__ U, unsigned char* __restrict__ U8,
    unsigned char* __restrict__ V8)
{
    __shared__ __bf16 Sm[128 * 264];  // As (stride 264) / Hs (stride 136) / Os

    const int tid  = threadIdx.x;
    const int row0 = blockIdx.x * 128;
    const int wave = tid >> 6, lane = tid & 63;
    const int lm = lane & 15, lq = lane >> 4;

    // ---- stage X tile: all 32 loads in flight (NT), then cvt+write ----
    floatx4 xa[32];
    #pragma unroll
    for (int it = 0; it < 32; ++it) {
        int f4  = it * 256 + tid;                 // 0..8191
        int row = f4 >> 6, c4 = f4 & 63;
        int grow = row0 + row; if (grow >= L_NODES) grow = L_NODES - 1;
        xa[it] = __builtin_nontemporal_load(
                     reinterpret_cast<const floatx4*>(X + (size_t)grow * NFEAT + c4 * 4));
    }
    #pragma unroll
    for (int it = 0; it < 32; ++it) {
        int f4  = it * 256 + tid;
        int row = f4 >> 6, c4 = f4 & 63;
        bf16x4 o;
        o[0]=(__bf16)xa[it][0]; o[1]=(__bf16)xa[it][1];
        o[2]=(__bf16)xa[it][2]; o[3]=(__bf16)xa[it][3];
        *(bf16x4*)&Sm[row * 264 + c4 * 4] = o;
    }

    // b1 panel (phase-1 only); latency hides under the barrier.
    bf16x8 b1[2][8];
    #pragma unroll
    for (int nt = 0; nt < 2; ++nt) {
        int ntg = wave * 2 + nt;
        #pragma unroll
        for (int ks = 0; ks < 8; ++ks)
            b1[nt][ks] = *(const bf16x8*)(WtH + (size_t)(ntg * 16 + lm) * 256 + ks * 32 + lq * 8);
    }
    __syncthreads();                                          // bar1: As ready

    // ---- phase 1: H = relu(X @ Wh + b), 128 rows ----
    floatx4 acc1[8][2] = {};
    #pragma unroll
    for (int ks = 0; ks < 8; ++ks) {
        bf16x8 af[8];
        #pragma unroll
        for (int t = 0; t < 8; ++t)
            af[t] = *(const bf16x8*)&Sm[(t * 16 + lm) * 264 + ks * 32 + lq * 8];
        #pragma unroll
        for (int t = 0; t < 8; ++t)
            #pragma unroll
            for (int nt = 0; nt < 2; ++nt)
                acc1[t][nt] = __builtin_amdgcn_mfma_f32_16x16x32_bf16(
                    af[t], b1[nt][ks], acc1[t][nt], 0, 0, 0);
    }
    __syncthreads();                                          // bar2: As reads closed

    // write Hs (stride 136; aliases As — As dead)
    #pragma unroll
    for (int nt = 0; nt < 2; ++nt) {
        int col = (wave * 2 + nt) * 16 + lm;
        float bias = b[col];
        #pragma unroll
        for (int t = 0; t < 8; ++t)
            #pragma unroll
            for (int p = 0; p < 4; ++p)
                Sm[(t * 16 + lq * 4 + p) * 136 + col] =
                    (__bf16)fmaxf(acc1[t][nt][p] + bias, 0.f);
    }
    __syncthreads();                                          // bar3: Hs ready

    // ---- phase 2: two ks-passes (h=0,1); both acc halves stay live ----
    floatx4 acc2a[8][2] = {}, acc2b[8][2] = {};
    {
        bf16x8 b2h[2][4];
        #pragma unroll
        for (int nt = 0; nt < 2; ++nt) {
            int ntg = wave * 4 + nt;                          // h = 0
            #pragma unroll
            for (int ks = 0; ks < 4; ++ks)
                b2h[nt][ks] = *(const bf16x8*)(WtG2 + (size_t)(ntg * 16 + lm) * 128 + ks * 32 + lq * 8);
        }
        #pragma unroll
        for (int ks = 0; ks < 4; ++ks) {
            bf16x8 af[8];
            #pragma unroll
            for (int t = 0; t < 8; ++t)
                af[t] = *(const bf16x8*)&Sm[(t * 16 + lm) * 136 + ks * 32 + lq * 8];
            #pragma unroll
            for (int t = 0; t < 8; ++t)
                #pragma unroll
                for (int nt = 0; nt < 2; ++nt)
                    acc2a[t][nt] = __builtin_amdgcn_mfma_f32_16x16x32_bf16(
                        af[t], b2h[nt][ks], acc2a[t][nt], 0, 0, 0);
        }
    }
    {
        bf16x8 b2h[2][4];
        #pragma unroll
        for (int nt = 0; nt < 2; ++nt) {
            int ntg = wave * 4 + 2 + nt;                      // h = 1
            #pragma unroll
            for (int ks = 0; ks < 4; ++ks)
                b2h[nt][ks] = *(const bf16x8*)(WtG2 + (size_t)(ntg * 16 + lm) * 128 + ks * 32 + lq * 8);
        }
        #pragma unroll
        for (int ks = 0; ks < 4; ++ks) {
            bf16x8 af[8];
            #pragma unroll
            for (int t = 0; t < 8; ++t)
                af[t] = *(const bf16x8*)&Sm[(t * 16 + lm) * 136 + ks * 32 + lq * 8];
            #pragma unroll
            for (int t = 0; t < 8; ++t)
                #pragma unroll
                for (int nt = 0; nt < 2; ++nt)
                    acc2b[t][nt] = __builtin_amdgcn_mfma_f32_16x16x32_bf16(
                        af[t], b2h[nt][ks], acc2b[t][nt], 0, 0, 0);
        }
    }
    __syncthreads();                                          // bar4: Hs reads closed

    // write Os (stride 264; aliases Hs — Hs dead); cols 0..127 = U, 128..255 = V
    #pragma unroll
    for (int h = 0; h < 2; ++h)
        #pragma unroll
        for (int nt = 0; nt < 2; ++nt) {
            int col = (wave * 4 + h * 2 + nt) * 16 + lm;
            #pragma unroll
            for (int t = 0; t < 8; ++t)
                #pragma unroll
                for (int p = 0; p < 4; ++p)
                    Sm[(t * 16 + lq * 4 + p) * 264 + col] =
                        (__bf16)(h ? acc2b[t][nt][p] : acc2a[t][nt][p]);
        }
    __syncthreads();                                          // bar5: Os ready

    // U bf16 store (cols 0..127): 8 its, coalesced
    #pragma unroll
    for (int it = 0; it < 8; ++it) {
        int fid = it * 256 + tid;                 // 0..2047
        int row = fid >> 4, c8 = fid & 15;
        int grow = row0 + row;
        if (grow < L_NODES)
            *(bf16x8*)(U + (size_t)grow * JDIM + c8 * 8) =
                *(bf16x8*)&Sm[row * 264 + c8 * 8];
    }
    // fp8 copies (U8 from cols 0..127, V8 from cols 128..255): 16 its, 8B/job
    #pragma unroll
    for (int it = 0; it < 16; ++it) {
        int fid = it * 256 + tid;                 // 0..4095
        int row = fid >> 5, c8 = fid & 31;
        int grow = row0 + row;
        if (grow < L_NODES) {
            int col = c8 * 8;
            bf16x8 v = *(bf16x8*)&Sm[row * 264 + col];
            unsigned int lo0 = f32x2_to_fp8x2((float)v[0], (float)v[1]);
            unsigned int hi0 = f32x2_to_fp8x2((float)v[2], (float)v[3]);
            unsigned int lo1 = f32x2_to_fp8x2((float)v[4], (float)v[5]);
            unsigned int hi1 = f32x2_to_fp8x2((float)v[6], (float)v[7]);
            uint2 o;
            o.x = (lo0 & 0xffffu) | (hi0 << 16);
            o.y = (lo1 & 0xffffu) | (hi1 << 16);
            if (col < 128) *(uint2*)(U8 + (size_t)grow * JDIM + col) = o;
            else           *(uint2*)(V8 + (size_t)grow * JDIM + (col - 128)) = o;
        }
    }
}

// ---------------------------------------------------------------------------
// Kernel 2 (fused gather + final).  R21: phase-A gather reads the fp8 rows
// (128B each) — request volume 410 -> 205 MB, 2 cache lines/row instead of 4.
// Decode via v_cvt_pk_f32_fp8 (2 el/instr; VALU has headroom at 33%).
// E2's direct U term still reads bf16 U (sequential Us tile) — full precision
// where it matters.  Structure otherwise unchanged from R13.
// ---------------------------------------------------------------------------
__global__ __launch_bounds__(256, 4) void k_gfinal(
    const __bf16* __restrict__ U, const unsigned char* __restrict__ U8,
    const unsigned char* __restrict__ V8,
    const __bf16* __restrict__ WtGv, const float* __restrict__ bg,
    const float* __restrict__ Wf, const float* __restrict__ bf,
    const int* __restrict__ idx0, const int* __restrict__ idx1,
    float* __restrict__ out)
{
    __shared__ int    sidx[2][8][64];               // 4 KB; part[] aliases this
    __shared__ __bf16 E1s[64 * 136];                // 17.4 KB
    __shared__ __bf16 Us [64 * 136];                // 17.4 KB
    float (*part)[64][2] = (float (*)[64][2])&sidx[0][0][0];   // 2 KB alias

    const int tid  = threadIdx.x;
    const int row0 = blockIdx.x * 64;
    const int wave = tid >> 6, lane = tid & 63;
    const int lm = lane & 15, lq = lane >> 4;

    // stage indices (1024 ints, 4/thread, NT) and U tile (4 bf16x8/thread)
    #pragma unroll
    for (int it = 0; it < 4; ++it) {
        int fid = it * 256 + tid;                 // 0..1023
        int m = fid >> 9, rem = fid & 511;
        int s = rem >> 6, il = rem & 63;
        int gr = row0 + il; if (gr >= L_NODES) gr = L_NODES - 1;
        const int* ip = (m ? idx1 : idx0) + (size_t)s * L_NODES + gr;
        sidx[m][s][il] = __builtin_nontemporal_load(ip);
    }
    #pragma unroll
    for (int it = 0; it < 4; ++it) {
        int fid = it * 256 + tid;                 // 0..1023
        int r = fid >> 4, c8 = fid & 15;
        int g = row0 + r; if (g >= L_NODES) g = L_NODES - 1;
        *(bf16x8*)&Us[r * 136 + c8 * 8] = *(const bf16x8*)(U + (size_t)g * JDIM + c8 * 8);
    }
    __syncthreads();

    // ---- phase A: fp8 gather-add into E1s (2-deep pipelined) ----
    {
        const int c0 = (tid & 15) * 8;            // col (and byte) chunk
        const int rb = tid >> 4;                  // row base 0..15 (+16k)
        float bias[8];
        *(float4*)&bias[0] = *(const float4*)(bg + c0);
        *(float4*)&bias[4] = *(const float4*)(bg + c0 + 4);

        float acc[4][8] = {};
        uint2 uA[4], vA[4], uB[4], vB[4];

        auto LOADP = [&](int s, uint2 (&uu)[4], uint2 (&vv)[4]) {
            #pragma unroll
            for (int rr = 0; rr < 4; ++rr) {
                int r = rb + rr * 16;
                int a0 = sidx[0][s][r], a1 = sidx[1][s][r];
                uu[rr] = *(const uint2*)(U8 + (size_t)a0 * JDIM + c0);
                vv[rr] = *(const uint2*)(V8 + (size_t)a1 * JDIM + c0);
            }
        };
        auto ACCUM = [&](uint2 (&uu)[4], uint2 (&vv)[4]) {
            #pragma unroll
            for (int rr = 0; rr < 4; ++rr) {
                floatx2 u0 = fp8x2_to_f32x2(uu[rr].x);
                floatx2 u1 = fp8x2_to_f32x2(uu[rr].x >> 16);
                floatx2 u2 = fp8x2_to_f32x2(uu[rr].y);
                floatx2 u3 = fp8x2_to_f32x2(uu[rr].y >> 16);
                floatx2 w0 = fp8x2_to_f32x2(vv[rr].x);
                floatx2 w1 = fp8x2_to_f32x2(vv[rr].x >> 16);
                floatx2 w2 = fp8x2_to_f32x2(vv[rr].y);
                floatx2 w3 = fp8x2_to_f32x2(vv[rr].y >> 16);
                acc[rr][0] += fmaxf(u0[0] + w0[0] + bias[0], 0.f);
                acc[rr][1] += fmaxf(u0[1] + w0[1] + bias[1], 0.f);
                acc[rr][2] += fmaxf(u1[0] + w1[0] + bias[2], 0.f);
                acc[rr][3] += fmaxf(u1[1] + w1[1] + bias[3], 0.f);
                acc[rr][4] += fmaxf(u2[0] + w2[0] + bias[4], 0.f);
                acc[rr][5] += fmaxf(u2[1] + w2[1] + bias[5], 0.f);
                acc[rr][6] += fmaxf(u3[0] + w3[0] + bias[6], 0.f);
                acc[rr][7] += fmaxf(u3[1] + w3[1] + bias[7], 0.f);
            }
        };

        LOADP(0, uA, vA);
        #pragma unroll
        for (int s = 0; s < 8; ++s) {
            if ((s & 1) == 0) {
                if (s < 7) LOADP(s + 1, uB, vB);
                ACCUM(uA, vA);
            } else {
                if (s < 7) LOADP(s + 1, uA, vA);
                ACCUM(uB, vB);
            }
        }

        #pragma unroll
        for (int rr = 0; rr < 4; ++rr) {
            int r = rb + rr * 16;
            bf16x8 o;
            #pragma unroll
            for (int p = 0; p < 8; ++p)
                o[p] = (__bf16)fmaxf(acc[rr][p] * 0.125f, 0.f);
            *(bf16x8*)&E1s[r * 136 + c0] = o;
        }
    }
    __syncthreads();   // also closes all sidx reads before part[] writes

    // B panel (phase-B-only): load now so it doesn't hold VGPRs in phase A
    bf16x8 b3[2][4];
    #pragma unroll
    for (int nt = 0; nt < 2; ++nt) {
        int ntg = wave * 2 + nt;
        #pragma unroll
        for (int ks = 0; ks < 4; ++ks)
            b3[nt][ks] = *(const bf16x8*)(WtGv + (size_t)(ntg * 16 + lm) * 128 + ks * 32 + lq * 8);
    }

    // ---- phase B: E2 = relu(U + E1 @ Wg_bot + bg); head ----
    floatx4 acc[4][2] = {};
    #pragma unroll
    for (int ks = 0; ks < 4; ++ks) {
        bf16x8 af[4];
        #pragma unroll
        for (int t = 0; t < 4; ++t)
            af[t] = *(const bf16x8*)&E1s[(t * 16 + lm) * 136 + ks * 32 + lq * 8];
        #pragma unroll
        for (int t = 0; t < 4; ++t)
            #pragma unroll
            for (int nt = 0; nt < 2; ++nt)
                acc[t][nt] = __builtin_amdgcn_mfma_f32_16x16x32_bf16(
                    af[t], b3[nt][ks], acc[t][nt], 0, 0, 0);
    }

    float bias[2], wf0[2], wf1[2];
    #pragma unroll
    for (int nt = 0; nt < 2; ++nt) {
        int col = (wave * 2 + nt) * 16 + lm;
        bias[nt] = bg[col];
        wf0[nt] = Wf[col * 2 + 0];
        wf1[nt] = Wf[col * 2 + 1];
    }
    #pragma unroll
    for (int t = 0; t < 4; ++t) {
        float p0[4], p1[4];
        #pragma unroll
        for (int p = 0; p < 4; ++p) {
            int r = t * 16 + lq * 4 + p;
            float a0 = 0.f, a1 = 0.f;
            #pragma unroll
            for (int nt = 0; nt < 2; ++nt) {
                int col = (wave * 2 + nt) * 16 + lm;
                float e2 = fmaxf((float)Us[r * 136 + col] + acc[t][nt][p] + bias[nt], 0.f);
                a0 = fmaf(e2, wf0[nt], a0);
                a1 = fmaf(e2, wf1[nt], a1);
            }
            p0[p] = a0; p1[p] = a1;
        }
        #pragma unroll
        for (int m = 1; m <= 8; m <<= 1)
            #pragma unroll
            for (int p = 0; p < 4; ++p) {
                p0[p] += __shfl_xor(p0[p], m, 16);
                p1[p] += __shfl_xor(p1[p], m, 16);
            }
        if (lm == 0)
            #pragma unroll
            for (int p = 0; p < 4; ++p) {
                part[wave][t * 16 + lq * 4 + p][0] = p0[p];
                part[wave][t * 16 + lq * 4 + p][1] = p1[p];
            }
    }
    __syncthreads();

    if (tid < 128) {
        int row = tid >> 1, o = tid & 1;
        int grow = row0 + row;
        if (grow < L_NODES) {
            float v = part[0][row][o] + part[1][row][o] + part[2][row][o]
                    + part[3][row][o] + bf[o];
            __builtin_nontemporal_store(v, &out[(size_t)grow * 2 + o]);
        }
    }
}

// ---------------------------------------------------------------------------
extern "C" void kernel_launch(void* const* d_in, const int* in_sizes, int n_in,
                              void* d_out, int out_size, void* d_ws, size_t ws_size,
                              hipStream_t stream) {
    const float* X    = (const float*)d_in[0];
    const float* W_h1 = (const float*)d_in[1];
    const float* b_h1 = (const float*)d_in[2];
    const float* W_g1 = (const float*)d_in[3];
    const float* b_g1 = (const float*)d_in[4];
    const float* W_f  = (const float*)d_in[5];
    const float* b_f  = (const float*)d_in[6];
    const int*   idx0 = (const int*)d_in[7];
    const int*   idx1 = (const int*)d_in[8];
    float* out = (float*)d_out;

    __bf16*        U   = (__bf16*)d_ws;                       // 25.6 MB
    unsigned char* U8  = (unsigned char*)(U + (size_t)L_NODES * JDIM);  // 12.8 MB
    unsigned char* V8  = U8 + (size_t)L_NODES * JDIM;         // 12.8 MB
    __bf16*        WtH = (__bf16*)(V8 + (size_t)L_NODES * JDIM);        // 64 KB
    __bf16*        WtG2 = WtH + 32768;                        // 64 KB
    __bf16*        WtGv = WtG2 + 128 * 128;                   // alias: rows 128..

    k_prep<<<128, 256, 0, stream>>>(W_h1, W_g1, WtH, WtG2);
    k_h1uv<<<(L_NODES + 127) / 128, 256, 0, stream>>>(X, WtH, WtG2, b_h1, U, U8, V8);
    k_gfinal<<<(L_NODES + 63) / 64, 256, 0, stream>>>(U, U8, V8, WtGv, b_g1, W_f, b_f,
                                                      idx0, idx1, out);
}